// Round 5
// baseline (540.201 us; speedup 1.0000x reference)
//
#include <hip/hip_runtime.h>

#define BIMG 8
#define NBOX 100000
#define NCLS 80
#define KDET 300
#define CAP2 8192               // common-path per-image candidate cap
#define PCCAP 2048              // rare-path per-class push cap
#define BUFSTRIDE (NCLS * PCCAP)   // 163840 keys per image slice
#define TPUSH2 0.999755859375f  // 1 - 2^-12: E[count]=1953 per image (sd 44)
#define SCORE_T 0.05f
#define NELEM 8000000           // N*C per image
#define NQ    2000000           // float4s per image

typedef unsigned long long u64;
typedef unsigned u32;

// workspace layout (bytes)
#define OFF_PCNT 0u             // 8*4 = 32
#define ZERO_BYTES 32u
#define OFF_BUF  4096u          // 8 * 163840 * 8 = 10.49 MB

static __device__ __forceinline__ u64 shr64(u64 v, int s) {
  return (s >= 64) ? 0ull : (v >> s);
}
// total-order key: score desc, then (c,n) asc on ties — simultaneously the
// per-class NMS processing order AND the reference's output tie-order.
static __device__ __forceinline__ u64 key2(float sc, u32 c, u32 n) {
  return ((u64)__float_as_uint(sc) << 32) | (u32)(~(c * (u32)NBOX + n));
}

// One radix-select step over hist[2048], executed by wave 0.
// Finds bin of the sk-th largest (from top), spfx = (spfx<<11)|bin, updates sk.
// ssel = #keys in current subset with digit >= chosen bin (for early-exit).
static __device__ __forceinline__ void radix_step(const u32* hist, u32* sk,
                                                  u64* spfx, u32* ssel) {
  if (threadIdx.x < 64) {
    const int lane = threadIdx.x;
    const int chunk = 32;                // 2048/64
    u32 psum = 0;
    for (int i = 0; i < chunk; ++i) psum += hist[lane * chunk + i];
    u32 suf = psum;
#pragma unroll
    for (int off = 1; off < 64; off <<= 1) {
      u32 o = __shfl_down(suf, off);
      if (lane + off < 64) suf += o;
    }
    u32 k = *sk;
    u64 bal = __ballot(suf >= k);
    if (bal != 0ull) {
      int L = 63 - __clzll((long long)bal);
      if (lane == L) {
        u32 krem = k - (suf - psum);
        int bi = (L + 1) * chunk - 1;
        u32 acc = 0;
        for (;;) {
          acc += hist[bi];
          if (acc >= krem || bi == L * chunk) break;
          --bi;
        }
        *spfx = (*spfx << 11) | (u32)bi;
        *sk = krem - (acc - hist[bi]);
        *ssel = (suf - psum) + acc;
      }
    }
  }
}

// ---------------- pass A: streaming threshold filter (no staging) ----------------
__global__ __launch_bounds__(256) void histK(const float* __restrict__ cls,
                                             u32* __restrict__ pcnt,
                                             u64* __restrict__ buf) {
  const int t = threadIdx.x;
  const int b = blockIdx.y;
  const float4* base4 = (const float4*)(cls + (size_t)b * NELEM);
  u64* bufb = buf + (size_t)b * BUFSTRIDE;
  const int start = blockIdx.x * 8192;   // 245 blocks/img * 8192 float4 >= 2M

#define PUSH1(cc, sc_) do { \
    u32 g = atomicAdd(&pcnt[b], 1u); \
    if (g < CAP2) bufb[g] = key2(sc_, (u32)(cc), (u32)n); } while (0)
#define PROCQ(u) do { \
    float mx = fmaxf(fmaxf(v##u.x, v##u.y), fmaxf(v##u.z, v##u.w)); \
    if (mx >= TPUSH2) { \
      const int e0 = q##u * 4; \
      const int c0 = e0 % NCLS; \
      const int n = e0 / NCLS; \
      if (v##u.x >= TPUSH2) PUSH1(c0 + 0, v##u.x); \
      if (v##u.y >= TPUSH2) PUSH1(c0 + 1, v##u.y); \
      if (v##u.z >= TPUSH2) PUSH1(c0 + 2, v##u.z); \
      if (v##u.w >= TPUSH2) PUSH1(c0 + 3, v##u.w); \
    } } while (0)

  if (start + 8192 <= NQ) {            // full blocks: no bounds checks
    for (int it = 0; it < 4; ++it) {
      const int qb = start + it * 2048 + t;
#define LOADF(u) const int q##u = qb + (u) * 256; const float4 v##u = base4[q##u]
      LOADF(0); LOADF(1); LOADF(2); LOADF(3);
      LOADF(4); LOADF(5); LOADF(6); LOADF(7);
#undef LOADF
      PROCQ(0); PROCQ(1); PROCQ(2); PROCQ(3);
      PROCQ(4); PROCQ(5); PROCQ(6); PROCQ(7);
    }
  } else {                              // tail block: checked loads
    for (int it = 0; it < 4; ++it) {
      const int qb = start + it * 2048 + t;
#define LOADC(u) const int q##u = qb + (u) * 256; \
  const float4 v##u = (q##u < NQ) ? base4[q##u] : make_float4(0.f, 0.f, 0.f, 0.f)
      LOADC(0); LOADC(1); LOADC(2); LOADC(3);
      LOADC(4); LOADC(5); LOADC(6); LOADC(7);
#undef LOADC
      PROCQ(0); PROCQ(1); PROCQ(2); PROCQ(3);
      PROCQ(4); PROCQ(5); PROCQ(6); PROCQ(7);
    }
  }
#undef PROCQ
#undef PUSH1
}

// ---------------- per image: chunked global NMS in total key order ----------------
// Common path: select top-512 candidates (key desc), one class-masked greedy NMS,
// first 300 kept = output. Rare paths (overflow / <300 kept) refill exactly.
__global__ __launch_bounds__(1024) void nmsK(const float* __restrict__ boxes,
                                             const float* __restrict__ cls,
                                             const u32* __restrict__ pcnt,
                                             u64* __restrict__ buf,
                                             float* __restrict__ out) {
  __shared__ u64 msk[512][8];        // 32 KB; head aliased as hist[2048] + tkbuf[512]
  __shared__ u64 ks[512];            // 4 KB   sorted chunk keys
  __shared__ float bx[512][5];       // 10 KB  chunk boxes (stride-5)
  __shared__ u32 ci[512];            // 2 KB   chunk classes
  __shared__ u32 valid[512];         // 2 KB
  __shared__ u64 kkey[KDET];         // kept keys (output order)
  __shared__ float kbx[KDET][4];     // kept boxes
  __shared__ u32 ccnt[NCLS], chunkcls[NCLS];
  __shared__ u64 keptw[8];
  __shared__ u64 sand, sor, spfx, swin;
  __shared__ u32 sk, ssel, stcnt, srem, skcnt, scap;
  __shared__ u32 srtot, sfpfx, sfk, sfab, sfeq, sfmode, slocal;

  u32* hist = (u32*)&msk[0][0];              // bytes [0, 8192)
  u64* tkbuf = (u64*)&msk[0][0] + 1024;      // bytes [8192, 12288)
  const int t = threadIdx.x;
  const int b = blockIdx.x;
  volatile u64* bufb = (volatile u64*)(buf + (size_t)b * BUFSTRIDE);

  u32 cnt = pcnt[b];
  bool rare = (cnt > CAP2);   // buffer overflow: candidate set incomplete

  for (;;) {   // at most 2 attempts (common, then exact refill)
    if (rare) {
      // ---- exact refill: per-class top-300 supersets from cls (never runs) ----
      if (t == 0) srtot = 0;
      __syncthreads();
      for (int c = 0; c < NCLS; ++c) {
        const float* col = cls + (size_t)b * NELEM + c;
        if (t == 0) { sfmode = 0u; slocal = 0u; }
        for (int r = 0; r < 3; ++r) {
          const int shift = (r == 0) ? 21 : (r == 1) ? 10 : 0;
          const int nb = (r == 2) ? 1024 : 2048;
          for (int i = t; i < nb; i += 1024) hist[i] = 0;
          __syncthreads();
          for (int n = t; n < NBOX; n += 1024) {
            float s2 = col[(size_t)n * NCLS];
            if (s2 > SCORE_T) {
              u32 u = __float_as_uint(s2);
              bool ok = (r == 0) || (r == 1 ? ((u >> 21) == (sfpfx >> 21))
                                            : ((u >> 10) == (sfpfx >> 10)));
              if (ok) atomicAdd(&hist[(u >> shift) & (u32)(nb - 1)], 1u);
            }
          }
          __syncthreads();
          if (t == 0) {
            if (r == 0) {
              u32 s = 0;
              for (int i = 0; i < nb; ++i) s += hist[i];
              if (s < KDET) sfmode = 1u;
            }
            if (sfmode == 0u) {
              u32 kk2 = (r == 0) ? (u32)KDET : sfk;
              u32 acc = 0;
              int bi = nb - 1;
              for (; bi >= 0; --bi) {
                if (acc + hist[bi] >= kk2) break;
                acc += hist[bi];
              }
              sfk = kk2 - acc;
              sfpfx = ((r == 0) ? 0u : sfpfx) | ((u32)bi << shift);
              if (r == 2) { sfeq = hist[bi]; sfab = KDET - sfk; }
            }
          }
          __syncthreads();
          if (sfmode == 1u) break;
        }
        const u32 base = srtot;
        if (sfmode == 1u) {
          for (int n = t; n < NBOX; n += 1024) {
            float s2 = col[(size_t)n * NCLS];
            if (s2 > SCORE_T) {
              u32 g = atomicAdd(&slocal, 1u);
              if (g < PCCAP) bufb[base + g] = key2(s2, (u32)c, (u32)n);
            }
          }
        } else {
          const u32 ustar = sfpfx;
          const u32 m = sfab, e = sfeq;
          if (m + e <= PCCAP) {
            for (int n = t; n < NBOX; n += 1024) {
              float s2 = col[(size_t)n * NCLS];
              if (s2 > SCORE_T && __float_as_uint(s2) >= ustar) {
                u32 g = atomicAdd(&slocal, 1u);
                if (g < PCCAP) bufb[base + g] = key2(s2, (u32)c, (u32)n);
              }
            }
          } else {
            for (int n = t; n < NBOX; n += 1024) {
              float s2 = col[(size_t)n * NCLS];
              if (s2 > SCORE_T && __float_as_uint(s2) > ustar) {
                u32 g = atomicAdd(&slocal, 1u);
                if (g < PCCAP) bufb[base + g] = key2(s2, (u32)c, (u32)n);
              }
            }
            __syncthreads();
            if (t == 0) {   // equals pushed ascending n = reference tie order
              u32 room = PCCAP - slocal, got = 0;
              for (int n = 0; n < NBOX && got < room; ++n) {
                float s2 = col[(size_t)n * NCLS];
                if (s2 > SCORE_T && __float_as_uint(s2) == ustar) {
                  u32 g = atomicAdd(&slocal, 1u);
                  if (g < PCCAP) bufb[base + g] = key2(s2, (u32)c, (u32)n);
                  ++got;
                }
              }
            }
          }
        }
        __syncthreads();
        if (t == 0) srtot = base + min(slocal, (u32)PCCAP);
        __syncthreads();
      }
      __threadfence_block();
      __syncthreads();
      cnt = srtot;
    }

    // ---- chunked NMS over candidates bufb[0..cnt) ----
    if (t == 0) { skcnt = 0u; swin = ~0ull; }
    for (int i = t; i < NCLS; i += 1024) ccnt[i] = 0u;
    __syncthreads();

    for (;;) {   // chunk loop (common path: exactly one iteration)
      if (t == 0) { sand = ~0ull; sor = 0ull; srem = 0u; stcnt = 0u; scap = 0u; }
      if (t < 512) tkbuf[t] = 0ull;
      for (int i = t; i < NCLS; i += 1024) chunkcls[i] = 0u;
      __syncthreads();
      {  // remaining count + AND/OR over {key < win}
        const u64 win = swin;
        u64 ka = ~0ull, ko = 0ull;
        u32 rc = 0;
        for (u32 idx = t; idx < cnt; idx += 1024) {
          u64 key = bufb[idx];
          if (key < win) { ka &= key; ko |= key; ++rc; }
        }
#pragma unroll
        for (int off = 32; off > 0; off >>= 1) {
          ka &= __shfl_xor(ka, off);
          ko |= __shfl_xor(ko, off);
          rc += __shfl_xor(rc, off);
        }
        if ((t & 63) == 0) {
          atomicAnd((unsigned long long*)&sand, (unsigned long long)ka);
          atomicOr((unsigned long long*)&sor, (unsigned long long)ko);
          atomicAdd(&srem, rc);
        }
      }
      __syncthreads();
      if (srem == 0u) break;          // candidates exhausted
      const u64 win = swin;
      const u32 G = min(512u, srem);
      int eshift = 0;
      u64 ethr = 1ull;
      const bool allsel = (srem <= 512u);
      if (!allsel) {
        const u64 kand = sand, kor = sor;
        const u64 W = kand ^ kor;     // srem>=2 distinct keys -> W != 0
        const int hv = 63 - __clzll((long long)W);
        int s = 11 * (hv / 11);
        if (t == 0) { spfx = shr64(kand, s + 11); sk = G; }
        __syncthreads();
        for (;;) {
          for (int i = t; i < 2048; i += 1024) hist[i] = 0u;
          __syncthreads();
          const u64 pfxHi = spfx;
          const u32 skPrev = sk;
          for (u32 idx = t; idx < cnt; idx += 1024) {
            u64 key = bufb[idx];
            if (key < win && shr64(key, s + 11) == pfxHi)
              atomicAdd(&hist[(u32)(key >> s) & 2047u], 1u);
          }
          __syncthreads();
          radix_step(hist, &sk, &spfx, &ssel);
          __syncthreads();
          if (G - skPrev + ssel <= 512u || s == 0) { eshift = s; break; }
          s -= 11;
        }
        ethr = spfx;   // selected = {key<win, key>>eshift >= ethr}, |sel| in [G,512]
      }
      // ballot-compact selected keys into tkbuf
      {
        const int lane = t & 63;
        const u64 lml = (1ull << lane) - 1ull;
        for (u32 i0 = 0; i0 < cnt; i0 += 1024) {
          const u32 idx = i0 + t;
          u64 key = (idx < cnt) ? bufb[idx] : 0ull;
          bool q = (key != 0ull) && (key < win) &&
                   (allsel || shr64(key, eshift) >= ethr);
          u64 bal = __ballot(q);
          u32 nw = (u32)__popcll(bal);
          if (nw) {
            u32 base = 0;
            if (lane == 0) base = atomicAdd(&stcnt, nw);
            base = __shfl(base, 0);
            if (q) {
              u32 pos = base + (u32)__popcll(bal & lml);
              if (pos < 512u) tkbuf[pos] = key;
            }
          }
        }
      }
      __syncthreads();
      const int S = min((int)stcnt, 512);

      // rank-by-counting sort fused with gather (keys unique)
      if (t < 512) {
        const u64 mykey = tkbuf[t];
        const int SU = (S + 7) & ~7;   // tkbuf pre-zeroed beyond S
        int rank = 0;
        for (int j = 0; j < SU; j += 8) {
#pragma unroll
          for (int jj = 0; jj < 8; ++jj) rank += (tkbuf[j + jj] > mykey) ? 1 : 0;
        }
        if (mykey != 0ull) {
          ks[rank] = mykey;
          u32 e2 = ~(u32)mykey;
          u32 c = e2 / (u32)NBOX;
          u32 n = e2 - c * (u32)NBOX;
          ci[rank] = c;
          const float4 bv = *(const float4*)(boxes + ((size_t)b * NBOX + n) * 4);
          bx[rank][0] = bv.x; bx[rank][1] = bv.y;
          bx[rank][2] = bv.z; bx[rank][3] = bv.w;
        }
        if (t >= S) { ks[t] = 0ull; }
        valid[t] = (t < S) ? 1u : 0u;
      }
      __syncthreads();
      if (t < S) atomicAdd(&chunkcls[ci[t]], 1u);
      __syncthreads();
      // per-class top-300 candidate cap (reference truncation) — never binds here
      if (t < NCLS && (ccnt[t] + chunkcls[t] > (u32)KDET)) atomicOr(&scap, 1u);
      __syncthreads();
      if (scap) {
        if (t < S) {
          u32 c = ci[t], r = ccnt[c];
          for (int j = 0; j < t; ++j) r += (ci[j] == c) ? 1u : 0u;
          if (r >= (u32)KDET) valid[t] = 0u;
        }
        __syncthreads();
      }
      // suppression by carried kept set (chunk >= 1 only)
      const int kc0 = (int)skcnt;
      if (kc0 > 0) {
        if (t < S && valid[t]) {
          const float x1 = bx[t][0], y1 = bx[t][1], x2 = bx[t][2], y2 = bx[t][3];
          const float a1 = (x2 - x1) * (y2 - y1);
          const u32 c = ci[t];
          const int ke = min(kc0, KDET);
          for (int k = 0; k < ke; ++k) {
            u32 kcls = (~(u32)kkey[k]) / (u32)NBOX;
            if (kcls != c) continue;
            float lx = fmaxf(x1, kbx[k][0]);
            float ly = fmaxf(y1, kbx[k][1]);
            float rx = fminf(x2, kbx[k][2]);
            float ry = fminf(y2, kbx[k][3]);
            float iw = fmaxf(rx - lx, 0.0f), ih = fmaxf(ry - ly, 0.0f);
            float inter = iw * ih;
            float a2 = (kbx[k][2] - kbx[k][0]) * (kbx[k][3] - kbx[k][1]);
            float uni = fmaxf(a1 + a2 - inter, 1e-7f);
            float iou = inter / uni;
            if (iou >= 0.5f) { valid[t] = 0u; break; }
          }
        }
        __syncthreads();
      }
      // suppression masks among chunk: same-class AND IoU >= 0.5, j < i
      for (int tau = t; tau < 512 * 8; tau += 1024) {
        const int i = tau >> 3;
        const int w = tau & 7;
        u64 m = 0ull;
        const int jb = w << 6;
        if (i < S && valid[i] && jb < i) {
          const int je = min(i, jb + 64);
          const float x1 = bx[i][0], y1 = bx[i][1], x2 = bx[i][2], y2 = bx[i][3];
          const float a1 = (x2 - x1) * (y2 - y1);
          const u32 c = ci[i];
          for (int j = jb; j < je; ++j) {
            if (ci[j] != c) continue;
            float lx = fmaxf(x1, bx[j][0]);
            float ly = fmaxf(y1, bx[j][1]);
            float rx = fminf(x2, bx[j][2]);
            float ry = fminf(y2, bx[j][3]);
            float iw = fmaxf(rx - lx, 0.0f), ih = fmaxf(ry - ly, 0.0f);
            float inter = iw * ih;
            float a2 = (bx[j][2] - bx[j][0]) * (bx[j][3] - bx[j][1]);
            float uni = fmaxf(a1 + a2 - inter, 1e-7f);
            float iou = inter / uni;   // true IEEE division: matches reference
            if (iou >= 0.5f) m |= 1ull << (j & 63);
          }
        }
        msk[i][w] = m;
      }
      __syncthreads();
      // wave-parallel greedy scan (monotone-ballot)
      if (t < 64) {
        u64 kwv[8];
#pragma unroll
        for (int w = 0; w < 8; ++w) {
          const int i = w * 64 + t;
          bool pb = (i < S) && valid[i];
          u64 mown = 0ull;
          if (pb) {
#pragma unroll
            for (int w2 = 0; w2 < 8; ++w2)
              if (w2 < w && (msk[i][w2] & kwv[w2])) pb = false;
            mown = msk[i][w];
          }
          u64 kv = 0ull;
          for (;;) {
            u64 bal = __ballot(pb && ((mown & kv) == 0ull));
            if (!bal) break;
            int p = __ffsll((unsigned long long)bal) - 1;
            kv |= 1ull << p;
            if (t == p) pb = false;
          }
          kwv[w] = kv;
          if (t == 0) keptw[w] = kv;
        }
      }
      __syncthreads();
      // append kept in chunk order (== global key order == output order)
      if (t < S) {
        if ((keptw[t >> 6] >> (t & 63)) & 1ull) {
          int g = kc0;
          for (int w = 0; w < (t >> 6); ++w) g += __popcll(keptw[w]);
          g += __popcll(keptw[t >> 6] & ((1ull << (t & 63)) - 1ull));
          if (g < KDET) {
            kkey[g] = ks[t];
            kbx[g][0] = bx[t][0]; kbx[g][1] = bx[t][1];
            kbx[g][2] = bx[t][2]; kbx[g][3] = bx[t][3];
          }
        }
      }
      if (t == 0) {
        int tot = 0;
        for (int w = 0; w < 8; ++w) tot += __popcll(keptw[w]);
        skcnt = (u32)(kc0 + tot);
        swin = ks[S - 1];            // strictly decreasing -> termination
      }
      if (t < NCLS) ccnt[t] += chunkcls[t];
      __syncthreads();
      if (skcnt >= (u32)KDET) break;
    }   // chunk loop

    if (skcnt >= (u32)KDET || rare) break;
    rare = true;   // exhausted with <300 kept above TPUSH2: exact refill
  }

  // outputs: boxes [B,K,4] | scores [B,K] | labels [B,K] (as float)
  __syncthreads();
  const int kc = min((int)skcnt, KDET);
  if (t < KDET) {
    float* ob = out + ((size_t)b * KDET + t) * 4;
    float* os = out + (size_t)BIMG * KDET * 4;
    float* ol = os + (size_t)BIMG * KDET;
    if (t < kc) {
      u64 key = kkey[t];
      u32 e2 = ~(u32)key;
      u32 c = e2 / (u32)NBOX;
      *(float4*)ob = make_float4(kbx[t][0], kbx[t][1], kbx[t][2], kbx[t][3]);
      os[(size_t)b * KDET + t] = __uint_as_float((u32)(key >> 32));
      ol[(size_t)b * KDET + t] = (float)c;
    } else {
      *(float4*)ob = make_float4(-1.f, -1.f, -1.f, -1.f);
      os[(size_t)b * KDET + t] = -1.f;
      ol[(size_t)b * KDET + t] = -1.f;
    }
  }
}

extern "C" void kernel_launch(void* const* d_in, const int* in_sizes, int n_in,
                              void* d_out, int out_size, void* d_ws, size_t ws_size,
                              hipStream_t stream) {
  const float* boxes = (const float*)d_in[0];
  const float* cls = (const float*)d_in[1];
  float* out = (float*)d_out;
  char* ws = (char*)d_ws;

  u32* pcnt = (u32*)(ws + OFF_PCNT);
  u64* buf = (u64*)(ws + OFF_BUF);

  (void)hipMemsetAsync(ws + OFF_PCNT, 0, ZERO_BYTES, stream);

  histK<<<dim3(245, BIMG), 256, 0, stream>>>(cls, pcnt, buf);
  nmsK<<<BIMG, 1024, 0, stream>>>(boxes, cls, pcnt, buf, out);
}

// Round 6
// 448.391 us; speedup vs baseline: 1.2048x; 1.2048x over previous
//
#include <hip/hip_runtime.h>

#define BIMG 8
#define NBOX 100000
#define NCLS 80
#define KDET 300
#define CAP2 8192               // common-path per-image candidate cap
#define PCCAP 2048              // rare-path per-class push cap
#define BUFSTRIDE (NCLS * PCCAP)   // 163840 keys per image slice
#define TPUSH2 0.999755859375f  // 1 - 2^-12: E[count]=1953 per image (sd 44)
#define SCORE_T 0.05f
#define NELEM 8000000           // N*C per image
#define NQ    2000000           // float4s per image
#define STCAP 64                // per-block LDS staging capacity (E[use]=8)

typedef unsigned long long u64;
typedef unsigned u32;

// workspace layout (bytes)
#define OFF_PCNT 0u             // 8*4 = 32
#define ZERO_BYTES 32u
#define OFF_BUF  4096u          // 8 * 163840 * 8 = 10.49 MB

static __device__ __forceinline__ u64 shr64(u64 v, int s) {
  return (s >= 64) ? 0ull : (v >> s);
}
// total-order key: score desc, then (c,n) asc on ties — simultaneously the
// per-class NMS processing order AND the reference's output tie-order.
static __device__ __forceinline__ u64 key2(float sc, u32 c, u32 n) {
  return ((u64)__float_as_uint(sc) << 32) | (u32)(~(c * (u32)NBOX + n));
}

// One radix-select step over hist[2048], executed by wave 0.
// Finds bin of the sk-th largest (from top), spfx = (spfx<<11)|bin, updates sk.
// ssel = #keys in current subset with digit >= chosen bin (for early-exit).
static __device__ __forceinline__ void radix_step(const u32* hist, u32* sk,
                                                  u64* spfx, u32* ssel) {
  if (threadIdx.x < 64) {
    const int lane = threadIdx.x;
    const int chunk = 32;                // 2048/64
    u32 psum = 0;
    for (int i = 0; i < chunk; ++i) psum += hist[lane * chunk + i];
    u32 suf = psum;
#pragma unroll
    for (int off = 1; off < 64; off <<= 1) {
      u32 o = __shfl_down(suf, off);
      if (lane + off < 64) suf += o;
    }
    u32 k = *sk;
    u64 bal = __ballot(suf >= k);
    if (bal != 0ull) {
      int L = 63 - __clzll((long long)bal);
      if (lane == L) {
        u32 krem = k - (suf - psum);
        int bi = (L + 1) * chunk - 1;
        u32 acc = 0;
        for (;;) {
          acc += hist[bi];
          if (acc >= krem || bi == L * chunk) break;
          --bi;
        }
        *spfx = (*spfx << 11) | (u32)bi;
        *sk = krem - (acc - hist[bi]);
        *ssel = (suf - psum) + acc;
      }
    }
  }
}

// ---------------- pass A: streaming threshold filter, two-level aggregation ------
// Per-block LDS staging + ONE ranged atomic reservation per block. This keeps
// same-address device-atomic count at ~245/image (vs ~15.6K when every push
// hit pcnt[b] directly — that serialized at ~12ns/op = ~190us, R5 lesson).
__global__ __launch_bounds__(256) void histK(const float* __restrict__ cls,
                                             u32* __restrict__ pcnt,
                                             u64* __restrict__ buf) {
  __shared__ u64 stage[STCAP];
  __shared__ u32 lcnt, sbase, scnt;

  const int t = threadIdx.x;
  const int b = blockIdx.y;
  const float4* base4 = (const float4*)(cls + (size_t)b * NELEM);
  u64* bufb = buf + (size_t)b * BUFSTRIDE;
  const int start = blockIdx.x * 8192;   // 245 blocks/img * 8192 float4 >= 2M

  if (t == 0) lcnt = 0u;
  __syncthreads();

#define PUSH1(cc, sc_) do { \
    u64 k_ = key2(sc_, (u32)(cc), (u32)n); \
    u32 slot = atomicAdd(&lcnt, 1u); \
    if (slot < (u32)STCAP) stage[slot] = k_; \
    else { u32 g = atomicAdd(&pcnt[b], 1u); if (g < CAP2) bufb[g] = k_; } \
  } while (0)
#define PROCQ(u) do { \
    float mx = fmaxf(fmaxf(v##u.x, v##u.y), fmaxf(v##u.z, v##u.w)); \
    if (mx >= TPUSH2) { \
      const int e0 = q##u * 4; \
      const int c0 = e0 % NCLS; \
      const int n = e0 / NCLS; \
      if (v##u.x >= TPUSH2) PUSH1(c0 + 0, v##u.x); \
      if (v##u.y >= TPUSH2) PUSH1(c0 + 1, v##u.y); \
      if (v##u.z >= TPUSH2) PUSH1(c0 + 2, v##u.z); \
      if (v##u.w >= TPUSH2) PUSH1(c0 + 3, v##u.w); \
    } } while (0)

  if (start + 8192 <= NQ) {            // full blocks: no bounds checks
    for (int it = 0; it < 4; ++it) {
      const int qb = start + it * 2048 + t;
#define LOADF(u) const int q##u = qb + (u) * 256; const float4 v##u = base4[q##u]
      LOADF(0); LOADF(1); LOADF(2); LOADF(3);
      LOADF(4); LOADF(5); LOADF(6); LOADF(7);
#undef LOADF
      PROCQ(0); PROCQ(1); PROCQ(2); PROCQ(3);
      PROCQ(4); PROCQ(5); PROCQ(6); PROCQ(7);
    }
  } else {                              // tail block: checked loads
    for (int it = 0; it < 4; ++it) {
      const int qb = start + it * 2048 + t;
#define LOADC(u) const int q##u = qb + (u) * 256; \
  const float4 v##u = (q##u < NQ) ? base4[q##u] : make_float4(0.f, 0.f, 0.f, 0.f)
      LOADC(0); LOADC(1); LOADC(2); LOADC(3);
      LOADC(4); LOADC(5); LOADC(6); LOADC(7);
#undef LOADC
      PROCQ(0); PROCQ(1); PROCQ(2); PROCQ(3);
      PROCQ(4); PROCQ(5); PROCQ(6); PROCQ(7);
    }
  }
#undef PROCQ
#undef PUSH1
  __syncthreads();

  if (t == 0) {
    u32 c2 = min(lcnt, (u32)STCAP);
    scnt = c2;
    sbase = c2 ? atomicAdd(&pcnt[b], c2) : 0u;   // one ranged reservation/block
  }
  __syncthreads();
  if ((u32)t < scnt) {
    u32 g = sbase + (u32)t;
    if (g < CAP2) bufb[g] = stage[t];
  }
}

// ---------------- per image: chunked global NMS in total key order ----------------
// Common path: select top-512 candidates (key desc), one class-masked greedy NMS,
// first 300 kept = output. Rare paths (overflow / <300 kept) refill exactly.
__global__ __launch_bounds__(1024) void nmsK(const float* __restrict__ boxes,
                                             const float* __restrict__ cls,
                                             const u32* __restrict__ pcnt,
                                             u64* __restrict__ buf,
                                             float* __restrict__ out) {
  __shared__ u64 msk[512][8];        // 32 KB; head aliased as hist[2048] + tkbuf[512]
  __shared__ u64 ks[512];            // 4 KB   sorted chunk keys
  __shared__ float bx[512][5];       // 10 KB  chunk boxes (stride-5)
  __shared__ u32 ci[512];            // 2 KB   chunk classes
  __shared__ u32 valid[512];         // 2 KB
  __shared__ u64 kkey[KDET];         // kept keys (output order)
  __shared__ float kbx[KDET][4];     // kept boxes
  __shared__ u32 ccnt[NCLS], chunkcls[NCLS];
  __shared__ u64 keptw[8];
  __shared__ u64 sand, sor, spfx, swin;
  __shared__ u32 sk, ssel, stcnt, srem, skcnt, scap;
  __shared__ u32 srtot, sfpfx, sfk, sfab, sfeq, sfmode, slocal;

  u32* hist = (u32*)&msk[0][0];              // bytes [0, 8192)
  u64* tkbuf = (u64*)&msk[0][0] + 1024;      // bytes [8192, 12288)
  const int t = threadIdx.x;
  const int b = blockIdx.x;
  volatile u64* bufb = (volatile u64*)(buf + (size_t)b * BUFSTRIDE);

  u32 cnt = pcnt[b];
  bool rare = (cnt > CAP2);   // buffer overflow: candidate set incomplete

  for (;;) {   // at most 2 attempts (common, then exact refill)
    if (rare) {
      // ---- exact refill: per-class top-300 supersets from cls (never runs) ----
      if (t == 0) srtot = 0;
      __syncthreads();
      for (int c = 0; c < NCLS; ++c) {
        const float* col = cls + (size_t)b * NELEM + c;
        if (t == 0) { sfmode = 0u; slocal = 0u; }
        for (int r = 0; r < 3; ++r) {
          const int shift = (r == 0) ? 21 : (r == 1) ? 10 : 0;
          const int nb = (r == 2) ? 1024 : 2048;
          for (int i = t; i < nb; i += 1024) hist[i] = 0;
          __syncthreads();
          for (int n = t; n < NBOX; n += 1024) {
            float s2 = col[(size_t)n * NCLS];
            if (s2 > SCORE_T) {
              u32 u = __float_as_uint(s2);
              bool ok = (r == 0) || (r == 1 ? ((u >> 21) == (sfpfx >> 21))
                                            : ((u >> 10) == (sfpfx >> 10)));
              if (ok) atomicAdd(&hist[(u >> shift) & (u32)(nb - 1)], 1u);
            }
          }
          __syncthreads();
          if (t == 0) {
            if (r == 0) {
              u32 s = 0;
              for (int i = 0; i < nb; ++i) s += hist[i];
              if (s < KDET) sfmode = 1u;
            }
            if (sfmode == 0u) {
              u32 kk2 = (r == 0) ? (u32)KDET : sfk;
              u32 acc = 0;
              int bi = nb - 1;
              for (; bi >= 0; --bi) {
                if (acc + hist[bi] >= kk2) break;
                acc += hist[bi];
              }
              sfk = kk2 - acc;
              sfpfx = ((r == 0) ? 0u : sfpfx) | ((u32)bi << shift);
              if (r == 2) { sfeq = hist[bi]; sfab = KDET - sfk; }
            }
          }
          __syncthreads();
          if (sfmode == 1u) break;
        }
        const u32 base = srtot;
        if (sfmode == 1u) {
          for (int n = t; n < NBOX; n += 1024) {
            float s2 = col[(size_t)n * NCLS];
            if (s2 > SCORE_T) {
              u32 g = atomicAdd(&slocal, 1u);
              if (g < PCCAP) bufb[base + g] = key2(s2, (u32)c, (u32)n);
            }
          }
        } else {
          const u32 ustar = sfpfx;
          const u32 m = sfab, e = sfeq;
          if (m + e <= PCCAP) {
            for (int n = t; n < NBOX; n += 1024) {
              float s2 = col[(size_t)n * NCLS];
              if (s2 > SCORE_T && __float_as_uint(s2) >= ustar) {
                u32 g = atomicAdd(&slocal, 1u);
                if (g < PCCAP) bufb[base + g] = key2(s2, (u32)c, (u32)n);
              }
            }
          } else {
            for (int n = t; n < NBOX; n += 1024) {
              float s2 = col[(size_t)n * NCLS];
              if (s2 > SCORE_T && __float_as_uint(s2) > ustar) {
                u32 g = atomicAdd(&slocal, 1u);
                if (g < PCCAP) bufb[base + g] = key2(s2, (u32)c, (u32)n);
              }
            }
            __syncthreads();
            if (t == 0) {   // equals pushed ascending n = reference tie order
              u32 room = PCCAP - slocal, got = 0;
              for (int n = 0; n < NBOX && got < room; ++n) {
                float s2 = col[(size_t)n * NCLS];
                if (s2 > SCORE_T && __float_as_uint(s2) == ustar) {
                  u32 g = atomicAdd(&slocal, 1u);
                  if (g < PCCAP) bufb[base + g] = key2(s2, (u32)c, (u32)n);
                  ++got;
                }
              }
            }
          }
        }
        __syncthreads();
        if (t == 0) srtot = base + min(slocal, (u32)PCCAP);
        __syncthreads();
      }
      __threadfence_block();
      __syncthreads();
      cnt = srtot;
    }

    // ---- chunked NMS over candidates bufb[0..cnt) ----
    if (t == 0) { skcnt = 0u; swin = ~0ull; }
    for (int i = t; i < NCLS; i += 1024) ccnt[i] = 0u;
    __syncthreads();

    for (;;) {   // chunk loop (common path: exactly one iteration)
      if (t == 0) { sand = ~0ull; sor = 0ull; srem = 0u; stcnt = 0u; scap = 0u; }
      if (t < 512) tkbuf[t] = 0ull;
      for (int i = t; i < NCLS; i += 1024) chunkcls[i] = 0u;
      __syncthreads();
      {  // remaining count + AND/OR over {key < win}
        const u64 win = swin;
        u64 ka = ~0ull, ko = 0ull;
        u32 rc = 0;
        for (u32 idx = t; idx < cnt; idx += 1024) {
          u64 key = bufb[idx];
          if (key < win) { ka &= key; ko |= key; ++rc; }
        }
#pragma unroll
        for (int off = 32; off > 0; off >>= 1) {
          ka &= __shfl_xor(ka, off);
          ko |= __shfl_xor(ko, off);
          rc += __shfl_xor(rc, off);
        }
        if ((t & 63) == 0) {
          atomicAnd((unsigned long long*)&sand, (unsigned long long)ka);
          atomicOr((unsigned long long*)&sor, (unsigned long long)ko);
          atomicAdd(&srem, rc);
        }
      }
      __syncthreads();
      if (srem == 0u) break;          // candidates exhausted
      const u64 win = swin;
      const u32 G = min(512u, srem);
      int eshift = 0;
      u64 ethr = 1ull;
      const bool allsel = (srem <= 512u);
      if (!allsel) {
        const u64 kand = sand, kor = sor;
        const u64 W = kand ^ kor;     // srem>=2 distinct keys -> W != 0
        const int hv = 63 - __clzll((long long)W);
        int s = 11 * (hv / 11);
        if (t == 0) { spfx = shr64(kand, s + 11); sk = G; }
        __syncthreads();
        for (;;) {
          for (int i = t; i < 2048; i += 1024) hist[i] = 0u;
          __syncthreads();
          const u64 pfxHi = spfx;
          const u32 skPrev = sk;
          for (u32 idx = t; idx < cnt; idx += 1024) {
            u64 key = bufb[idx];
            if (key < win && shr64(key, s + 11) == pfxHi)
              atomicAdd(&hist[(u32)(key >> s) & 2047u], 1u);
          }
          __syncthreads();
          radix_step(hist, &sk, &spfx, &ssel);
          __syncthreads();
          if (G - skPrev + ssel <= 512u || s == 0) { eshift = s; break; }
          s -= 11;
        }
        ethr = spfx;   // selected = {key<win, key>>eshift >= ethr}, |sel| in [G,512]
      }
      // ballot-compact selected keys into tkbuf
      {
        const int lane = t & 63;
        const u64 lml = (1ull << lane) - 1ull;
        for (u32 i0 = 0; i0 < cnt; i0 += 1024) {
          const u32 idx = i0 + t;
          u64 key = (idx < cnt) ? bufb[idx] : 0ull;
          bool q = (key != 0ull) && (key < win) &&
                   (allsel || shr64(key, eshift) >= ethr);
          u64 bal = __ballot(q);
          u32 nw = (u32)__popcll(bal);
          if (nw) {
            u32 base = 0;
            if (lane == 0) base = atomicAdd(&stcnt, nw);
            base = __shfl(base, 0);
            if (q) {
              u32 pos = base + (u32)__popcll(bal & lml);
              if (pos < 512u) tkbuf[pos] = key;
            }
          }
        }
      }
      __syncthreads();
      const int S = min((int)stcnt, 512);

      // rank-by-counting sort fused with gather (keys unique)
      if (t < 512) {
        const u64 mykey = tkbuf[t];
        const int SU = (S + 7) & ~7;   // tkbuf pre-zeroed beyond S
        int rank = 0;
        for (int j = 0; j < SU; j += 8) {
#pragma unroll
          for (int jj = 0; jj < 8; ++jj) rank += (tkbuf[j + jj] > mykey) ? 1 : 0;
        }
        if (mykey != 0ull) {
          ks[rank] = mykey;
          u32 e2 = ~(u32)mykey;
          u32 c = e2 / (u32)NBOX;
          u32 n = e2 - c * (u32)NBOX;
          ci[rank] = c;
          const float4 bv = *(const float4*)(boxes + ((size_t)b * NBOX + n) * 4);
          bx[rank][0] = bv.x; bx[rank][1] = bv.y;
          bx[rank][2] = bv.z; bx[rank][3] = bv.w;
        }
        if (t >= S) { ks[t] = 0ull; }
        valid[t] = (t < S) ? 1u : 0u;
      }
      __syncthreads();
      if (t < S) atomicAdd(&chunkcls[ci[t]], 1u);
      __syncthreads();
      // per-class top-300 candidate cap (reference truncation) — never binds here
      if (t < NCLS && (ccnt[t] + chunkcls[t] > (u32)KDET)) atomicOr(&scap, 1u);
      __syncthreads();
      if (scap) {
        if (t < S) {
          u32 c = ci[t], r = ccnt[c];
          for (int j = 0; j < t; ++j) r += (ci[j] == c) ? 1u : 0u;
          if (r >= (u32)KDET) valid[t] = 0u;
        }
        __syncthreads();
      }
      // suppression by carried kept set (chunk >= 1 only)
      const int kc0 = (int)skcnt;
      if (kc0 > 0) {
        if (t < S && valid[t]) {
          const float x1 = bx[t][0], y1 = bx[t][1], x2 = bx[t][2], y2 = bx[t][3];
          const float a1 = (x2 - x1) * (y2 - y1);
          const u32 c = ci[t];
          const int ke = min(kc0, KDET);
          for (int k = 0; k < ke; ++k) {
            u32 kcls = (~(u32)kkey[k]) / (u32)NBOX;
            if (kcls != c) continue;
            float lx = fmaxf(x1, kbx[k][0]);
            float ly = fmaxf(y1, kbx[k][1]);
            float rx = fminf(x2, kbx[k][2]);
            float ry = fminf(y2, kbx[k][3]);
            float iw = fmaxf(rx - lx, 0.0f), ih = fmaxf(ry - ly, 0.0f);
            float inter = iw * ih;
            float a2 = (kbx[k][2] - kbx[k][0]) * (kbx[k][3] - kbx[k][1]);
            float uni = fmaxf(a1 + a2 - inter, 1e-7f);
            float iou = inter / uni;
            if (iou >= 0.5f) { valid[t] = 0u; break; }
          }
        }
        __syncthreads();
      }
      // suppression masks among chunk: same-class AND IoU >= 0.5, j < i
      for (int tau = t; tau < 512 * 8; tau += 1024) {
        const int i = tau >> 3;
        const int w = tau & 7;
        u64 m = 0ull;
        const int jb = w << 6;
        if (i < S && valid[i] && jb < i) {
          const int je = min(i, jb + 64);
          const float x1 = bx[i][0], y1 = bx[i][1], x2 = bx[i][2], y2 = bx[i][3];
          const float a1 = (x2 - x1) * (y2 - y1);
          const u32 c = ci[i];
          for (int j = jb; j < je; ++j) {
            if (ci[j] != c) continue;
            float lx = fmaxf(x1, bx[j][0]);
            float ly = fmaxf(y1, bx[j][1]);
            float rx = fminf(x2, bx[j][2]);
            float ry = fminf(y2, bx[j][3]);
            float iw = fmaxf(rx - lx, 0.0f), ih = fmaxf(ry - ly, 0.0f);
            float inter = iw * ih;
            float a2 = (bx[j][2] - bx[j][0]) * (bx[j][3] - bx[j][1]);
            float uni = fmaxf(a1 + a2 - inter, 1e-7f);
            float iou = inter / uni;   // true IEEE division: matches reference
            if (iou >= 0.5f) m |= 1ull << (j & 63);
          }
        }
        msk[i][w] = m;
      }
      __syncthreads();
      // wave-parallel greedy scan (monotone-ballot)
      if (t < 64) {
        u64 kwv[8];
#pragma unroll
        for (int w = 0; w < 8; ++w) {
          const int i = w * 64 + t;
          bool pb = (i < S) && valid[i];
          u64 mown = 0ull;
          if (pb) {
#pragma unroll
            for (int w2 = 0; w2 < 8; ++w2)
              if (w2 < w && (msk[i][w2] & kwv[w2])) pb = false;
            mown = msk[i][w];
          }
          u64 kv = 0ull;
          for (;;) {
            u64 bal = __ballot(pb && ((mown & kv) == 0ull));
            if (!bal) break;
            int p = __ffsll((unsigned long long)bal) - 1;
            kv |= 1ull << p;
            if (t == p) pb = false;
          }
          kwv[w] = kv;
          if (t == 0) keptw[w] = kv;
        }
      }
      __syncthreads();
      // append kept in chunk order (== global key order == output order)
      if (t < S) {
        if ((keptw[t >> 6] >> (t & 63)) & 1ull) {
          int g = kc0;
          for (int w = 0; w < (t >> 6); ++w) g += __popcll(keptw[w]);
          g += __popcll(keptw[t >> 6] & ((1ull << (t & 63)) - 1ull));
          if (g < KDET) {
            kkey[g] = ks[t];
            kbx[g][0] = bx[t][0]; kbx[g][1] = bx[t][1];
            kbx[g][2] = bx[t][2]; kbx[g][3] = bx[t][3];
          }
        }
      }
      if (t == 0) {
        int tot = 0;
        for (int w = 0; w < 8; ++w) tot += __popcll(keptw[w]);
        skcnt = (u32)(kc0 + tot);
        swin = ks[S - 1];            // strictly decreasing -> termination
      }
      if (t < NCLS) ccnt[t] += chunkcls[t];
      __syncthreads();
      if (skcnt >= (u32)KDET) break;
    }   // chunk loop

    if (skcnt >= (u32)KDET || rare) break;
    rare = true;   // exhausted with <300 kept above TPUSH2: exact refill
  }

  // outputs: boxes [B,K,4] | scores [B,K] | labels [B,K] (as float)
  __syncthreads();
  const int kc = min((int)skcnt, KDET);
  if (t < KDET) {
    float* ob = out + ((size_t)b * KDET + t) * 4;
    float* os = out + (size_t)BIMG * KDET * 4;
    float* ol = os + (size_t)BIMG * KDET;
    if (t < kc) {
      u64 key = kkey[t];
      u32 e2 = ~(u32)key;
      u32 c = e2 / (u32)NBOX;
      *(float4*)ob = make_float4(kbx[t][0], kbx[t][1], kbx[t][2], kbx[t][3]);
      os[(size_t)b * KDET + t] = __uint_as_float((u32)(key >> 32));
      ol[(size_t)b * KDET + t] = (float)c;
    } else {
      *(float4*)ob = make_float4(-1.f, -1.f, -1.f, -1.f);
      os[(size_t)b * KDET + t] = -1.f;
      ol[(size_t)b * KDET + t] = -1.f;
    }
  }
}

extern "C" void kernel_launch(void* const* d_in, const int* in_sizes, int n_in,
                              void* d_out, int out_size, void* d_ws, size_t ws_size,
                              hipStream_t stream) {
  const float* boxes = (const float*)d_in[0];
  const float* cls = (const float*)d_in[1];
  float* out = (float*)d_out;
  char* ws = (char*)d_ws;

  u32* pcnt = (u32*)(ws + OFF_PCNT);
  u64* buf = (u64*)(ws + OFF_BUF);

  (void)hipMemsetAsync(ws + OFF_PCNT, 0, ZERO_BYTES, stream);

  histK<<<dim3(245, BIMG), 256, 0, stream>>>(cls, pcnt, buf);
  nmsK<<<BIMG, 1024, 0, stream>>>(boxes, cls, pcnt, buf, out);
}